// Round 1
// baseline (2098.835 us; speedup 1.0000x reference)
//
#include <hip/hip_runtime.h>
#include <hip/hip_bf16.h>
#include <cstdint>
#include <cstddef>

#define DEV __device__ __forceinline__

typedef __attribute__((ext_vector_type(8))) short short8;
typedef __attribute__((ext_vector_type(4))) float f32x4;

constexpr int Dm  = 256;
constexpr int Hn  = 8;
constexpr int Qn  = 128;
constexpr int Cn  = 512;
constexpr int Bn  = 4;

DEV unsigned short f2bf(float f){
  unsigned int u = __builtin_bit_cast(unsigned int, f);
  u += 0x7fffu + ((u >> 16) & 1u);
  return (unsigned short)(u >> 16);
}

DEV f32x4 mfma16(short8 a, short8 b, f32x4 c){
  return __builtin_amdgcn_mfma_f32_16x16x32_bf16(a, b, c, 0, 0, 0);
}

// fragment load from XOR-swizzled LDS tile; rowbytes = bytes per row
DEV short8 ldfrag(const unsigned short* buf, int rowbytes, int row0, int ks, int l){
  int r = row0 + (l & 15);
  int byte = (ks * 64 + ((l >> 4) * 16)) ^ ((r & 7) << 4);
  return *(const short8*)((const char*)buf + r * rowbytes + byte);
}

// ---------------------------------------------------------------- converts
__global__ __launch_bounds__(256) void convert_kernel(
    const float* s0, unsigned short* d0,   // in_proj 196608
    const float* s1, unsigned short* d1,   // attn_out 65536
    const float* s2, unsigned short* d2,   // mlp1 65536
    const float* s3, unsigned short* d3,   // mlp2 65536
    const float* s4, unsigned short* d4,   // v_w 65536
    const float* s5, unsigned short* d5,   // o_w 65536
    const float* s6, unsigned short* d6,   // ff1 262144
    const float* s7, unsigned short* d7,   // ff2 262144
    const float* s8, unsigned short* d8)   // memory 524288
{
  const int total = 196608 + 65536*5 + 262144*2 + 524288;
  for (int i = blockIdx.x * 256 + threadIdx.x; i < total; i += gridDim.x * 256){
    int j = i;
    if (j < 196608){ d0[j] = f2bf(s0[j]); continue; } j -= 196608;
    if (j < 65536) { d1[j] = f2bf(s1[j]); continue; } j -= 65536;
    if (j < 65536) { d2[j] = f2bf(s2[j]); continue; } j -= 65536;
    if (j < 65536) { d3[j] = f2bf(s3[j]); continue; } j -= 65536;
    if (j < 65536) { d4[j] = f2bf(s4[j]); continue; } j -= 65536;
    if (j < 65536) { d5[j] = f2bf(s5[j]); continue; } j -= 65536;
    if (j < 262144){ d6[j] = f2bf(s6[j]); continue; } j -= 262144;
    if (j < 262144){ d7[j] = f2bf(s7[j]); continue; } j -= 262144;
    d8[j] = f2bf(s8[j]);
  }
}

// ---------------------------------------------------------------- layernorm
// out = (x-mean)/sqrt(var+1e-5)*g + b ; optional f32 out, bf16 out, bf16(out+add)
__global__ __launch_bounds__(256) void ln_kernel(
    const float* __restrict__ in, const float* __restrict__ g, const float* __restrict__ bt,
    const float* __restrict__ addp,
    float* __restrict__ outF, unsigned short* __restrict__ outA, unsigned short* __restrict__ outB)
{
  const int r = blockIdx.x, t = threadIdx.x;
  float x = in[(size_t)r * 256 + t];
  float s = x, s2 = x * x;
  #pragma unroll
  for (int m = 1; m < 64; m <<= 1){ s += __shfl_xor(s, m, 64); s2 += __shfl_xor(s2, m, 64); }
  __shared__ float ls[8];
  int w = t >> 6, l = t & 63;
  if (l == 0){ ls[w] = s; ls[4 + w] = s2; }
  __syncthreads();
  s  = ls[0] + ls[1] + ls[2] + ls[3];
  s2 = ls[4] + ls[5] + ls[6] + ls[7];
  float mean = s * (1.f / 256.f);
  float var  = s2 * (1.f / 256.f) - mean * mean;
  float y = (x - mean) * rsqrtf(var + 1e-5f) * g[t] + bt[t];
  size_t o = (size_t)r * 256 + t;
  if (outF) outF[o] = y;
  if (outA) outA[o] = f2bf(y);
  if (outB) outB[o] = f2bf(y + addp[o]);
}

// ---------------------------------------------------------------- generic GEMM
// C[M,N] = act(alpha * A_bf16(M,K) @ W_bf16(N,K)^T + bias) (+resid); f32 and/or bf16 out
__global__ __launch_bounds__(256, 4) void gemm_kernel(
    const unsigned short* __restrict__ A, const unsigned short* __restrict__ W,
    const float* __restrict__ bias, const float* __restrict__ resid,
    float* __restrict__ Cf, unsigned short* __restrict__ Cb,
    int M, int N, int K, float alpha, int relu)
{
  __shared__ unsigned short As[64 * 64];
  __shared__ unsigned short Ws[64 * 64];
  const int tid = threadIdx.x;
  const int l = tid & 63;
  const int w = tid >> 6;
  const int wm = w >> 1, wn = w & 1;
  const int bm = blockIdx.x * 64, bn = blockIdx.y * 64;
  f32x4 acc[2][2] = {{{0,0,0,0},{0,0,0,0}},{{0,0,0,0},{0,0,0,0}}};

  for (int kc = 0; kc < K; kc += 64){
    __syncthreads();
    #pragma unroll
    for (int i = 0; i < 2; ++i){
      int idx = tid + i * 256;            // 512 chunks of 8 bf16
      int r = idx >> 3, s = idx & 7;
      int byte = (s * 16) ^ ((r & 7) << 4);
      *(short8*)((char*)As + r * 128 + byte) = *(const short8*)(A + (size_t)(bm + r) * K + kc + s * 8);
      *(short8*)((char*)Ws + r * 128 + byte) = *(const short8*)(W + (size_t)(bn + r) * K + kc + s * 8);
    }
    __syncthreads();
    #pragma unroll
    for (int ks = 0; ks < 2; ++ks){
      short8 af[2], bf[2];
      af[0] = ldfrag(As, 128, wm * 32,      ks, l);
      af[1] = ldfrag(As, 128, wm * 32 + 16, ks, l);
      bf[0] = ldfrag(Ws, 128, wn * 32,      ks, l);
      bf[1] = ldfrag(Ws, 128, wn * 32 + 16, ks, l);
      #pragma unroll
      for (int i = 0; i < 2; ++i)
        #pragma unroll
        for (int j = 0; j < 2; ++j)
          acc[i][j] = mfma16(af[i], bf[j], acc[i][j]);
    }
  }
  #pragma unroll
  for (int i = 0; i < 2; ++i)
  #pragma unroll
  for (int j = 0; j < 2; ++j){
    int col = bn + wn * 32 + j * 16 + (l & 15);
    float bv = bias ? bias[col] : 0.f;
    #pragma unroll
    for (int u = 0; u < 4; ++u){
      int row = bm + wm * 32 + i * 16 + ((l >> 4) << 2) + u;
      float v = alpha * acc[i][j][u] + bv;
      if (relu) v = fmaxf(v, 0.f);
      if (resid) v += resid[(size_t)row * N + col];
      if (Cf) Cf[(size_t)row * N + col] = v;
      if (Cb) Cb[(size_t)row * N + col] = f2bf(v);
    }
  }
}

// ---------------------------------------------------------------- self-attention
// per block: one (b,h). qkp (512,512) f32 [q|k], vp (512,256) f32. out bf16 (512,256)
__global__ __launch_bounds__(256) void attn_kernel(
    const float* __restrict__ qkp, const float* __restrict__ vp,
    unsigned short* __restrict__ attn_o)
{
  __shared__ float ks[128][33];
  __shared__ float vs[128][33];
  __shared__ float sc[128][129];
  const int bh = blockIdx.x;
  const int b = bh >> 3, h = bh & 7;
  const int tid = threadIdx.x;
  const int lrow = tid >> 1;
  const int half = tid & 1;
  {
    int s = tid >> 1;
    int d0 = half * 16;
    const float* kp = qkp + ((size_t)s * Bn + b) * 512 + 256 + h * 32 + d0;
    const float* vv = vp  + ((size_t)s * Bn + b) * 256 +       h * 32 + d0;
    #pragma unroll
    for (int d = 0; d < 16; d += 4){
      *(float4*)&ks[s][d0 + d] = *(const float4*)(kp + d);
      *(float4*)&vs[s][d0 + d] = *(const float4*)(vv + d);
    }
  }
  __syncthreads();
  float qv[32];
  const float* qp = qkp + ((size_t)lrow * Bn + b) * 512 + h * 32;
  #pragma unroll
  for (int d = 0; d < 32; ++d) qv[d] = qp[d];
  const float scale = 0.17677669529663687f;   // 1/sqrt(32)
  float mloc = -1e30f;
  for (int s2 = 0; s2 < 64; ++s2){
    int s = half * 64 + s2;
    float dot = 0.f;
    #pragma unroll
    for (int d = 0; d < 32; ++d) dot += qv[d] * ks[s][d];
    dot *= scale;
    sc[lrow][s] = dot;
    mloc = fmaxf(mloc, dot);
  }
  float m = fmaxf(mloc, __shfl_xor(mloc, 1, 64));
  float sum = 0.f;
  for (int s2 = 0; s2 < 64; ++s2){
    int s = half * 64 + s2;
    float e = __expf(sc[lrow][s] - m);
    sum += e;
    sc[lrow][s] = e;
  }
  sum += __shfl_xor(sum, 1, 64);
  float inv = 1.f / sum;
  float o[32];
  #pragma unroll
  for (int d = 0; d < 32; ++d) o[d] = 0.f;
  for (int s2 = 0; s2 < 64; ++s2){
    int s = half * 64 + s2;
    float e = sc[lrow][s];
    #pragma unroll
    for (int d = 0; d < 32; ++d) o[d] += e * vs[s][d];
  }
  #pragma unroll
  for (int d = 0; d < 32; ++d){
    o[d] += __shfl_xor(o[d], 1, 64);
    o[d] *= inv;
  }
  unsigned short* op = attn_o + ((size_t)lrow * Bn + b) * 256 + h * 32 + half * 16;
  #pragma unroll
  for (int d = 0; d < 16; ++d) op[d] = f2bf(o[half * 16 + d]);
}

// ---------------------------------------------------------------- relation branch (fused)
// one block per (q,b). online softmax over C per channel f.
// h  = relu(rel@W1 + A1[q,b,f] + M1[c,b,f])       (A1 = tgt2@W1+b1, M1 = -mem@W1)
// v2 = rel@Wv + Mv[c,b,f]                          (Mv = mem@Wv+vb)
// sim= (h@W2 + b2)/16 ; t = sum_c softmax_c(sim)*v2
__global__ __launch_bounds__(512, 2) void relation_kernel(
    const float* __restrict__ rel,
    const float* __restrict__ A1,
    const float* __restrict__ M1,
    const float* __restrict__ Mv,
    const unsigned short* __restrict__ W1,
    const unsigned short* __restrict__ Wv,
    const unsigned short* __restrict__ W2,
    const float* __restrict__ b2,
    unsigned short* __restrict__ outT)
{
  __shared__ char lds[128 * 512 * 2];             // relT 64KB | hT 64KB
  unsigned short* relT = (unsigned short*)lds;
  unsigned short* hT   = (unsigned short*)(lds + 128 * 512);
  float* redbuf = (float*)lds;                     // aliased after main loop

  const int bid = blockIdx.x;                      // q*4 + b
  const int q = bid >> 2, b = bid & 3;
  const int tid = threadIdx.x;
  const int w = tid >> 6;                          // wave 0..7, owns rows [16w,16w+16)
  const int l = tid & 63;
  const int row0 = w * 16;
  const int fl = l & 15;
  const int g4 = l >> 4;

  float sm[16], sl[16], sa[16];
  #pragma unroll
  for (int i = 0; i < 16; ++i){ sm[i] = -1e30f; sl[i] = 0.f; sa[i] = 0.f; }
  float vreg[16][4];
  const float* A1r = A1 + (size_t)bid * 256;

  for (int ct = 0; ct < 4; ++ct){
    const int c0 = ct * 128;
    // stage this wave's 16 rel rows as bf16, XOR-swizzled (strip-private, no barrier)
    #pragma unroll
    for (int r = 0; r < 16; ++r){
      int row = row0 + r;
      int c = c0 + row;
      const float4 v4 = *(const float4*)(rel + (((size_t)q * Cn + c) * Bn + b) * Dm + l * 4);
      unsigned short u0 = f2bf(v4.x), u1 = f2bf(v4.y), u2 = f2bf(v4.z), u3 = f2bf(v4.w);
      unsigned long long pk = (unsigned long long)u0 | ((unsigned long long)u1 << 16)
                            | ((unsigned long long)u2 << 32) | ((unsigned long long)u3 << 48);
      int byte = (l * 8) ^ ((row & 7) << 4);
      *(unsigned long long*)((char*)relT + row * 512 + byte) = pk;
    }
    short8 af[8];
    #pragma unroll
    for (int k = 0; k < 8; ++k) af[k] = ldfrag(relT, 512, row0, k, l);

    // GEMM1a: h = relu(rel@W1 + A1 + M1) -> hT (bf16)
    #pragma unroll 2
    for (int nt = 0; nt < 16; ++nt){
      f32x4 acc = {0,0,0,0};
      const unsigned short* Wp = W1 + (size_t)(nt * 16 + fl) * 256 + g4 * 8;
      #pragma unroll
      for (int k = 0; k < 8; ++k){
        short8 bf = *(const short8*)(Wp + k * 32);
        acc = mfma16(af[k], bf, acc);
      }
      int f = nt * 16 + fl;
      float a1v = A1r[f];
      #pragma unroll
      for (int u = 0; u < 4; ++u){
        int i = g4 * 4 + u;
        int c = c0 + row0 + i;
        float hv = acc[u] + a1v + M1[((size_t)c * Bn + b) * 256 + f];
        hv = fmaxf(hv, 0.f);
        int row = row0 + i;
        int byte = (f * 2) ^ ((row & 7) << 4);
        *(unsigned short*)((char*)hT + row * 512 + byte) = f2bf(hv);
      }
    }
    // GEMM1b: v2 = rel@Wv + Mv  (kept in registers, frag-aligned with GEMM2 output)
    #pragma unroll
    for (int nt = 0; nt < 16; ++nt){
      f32x4 acc = {0,0,0,0};
      const unsigned short* Wp = Wv + (size_t)(nt * 16 + fl) * 256 + g4 * 8;
      #pragma unroll
      for (int k = 0; k < 8; ++k){
        short8 bf = *(const short8*)(Wp + k * 32);
        acc = mfma16(af[k], bf, acc);
      }
      int f = nt * 16 + fl;
      #pragma unroll
      for (int u = 0; u < 4; ++u){
        int i = g4 * 4 + u;
        int c = c0 + row0 + i;
        vreg[nt][u] = acc[u] + Mv[((size_t)c * Bn + b) * 256 + f];
      }
    }
    // GEMM2: sim = (h@W2 + b2)/16, then online softmax update over the 16-row strip
    short8 hf[8];
    #pragma unroll
    for (int k = 0; k < 8; ++k) hf[k] = ldfrag(hT, 512, row0, k, l);
    #pragma unroll
    for (int nt = 0; nt < 16; ++nt){
      f32x4 acc = {0,0,0,0};
      const unsigned short* Wp = W2 + (size_t)(nt * 16 + fl) * 256 + g4 * 8;
      #pragma unroll
      for (int k = 0; k < 8; ++k){
        short8 bf = *(const short8*)(Wp + k * 32);
        acc = mfma16(hf[k], bf, acc);
      }
      int f = nt * 16 + fl;
      float b2v = b2[f];
      float s0 = (acc[0] + b2v) * 0.0625f, s1 = (acc[1] + b2v) * 0.0625f;
      float s2 = (acc[2] + b2v) * 0.0625f, s3 = (acc[3] + b2v) * 0.0625f;
      float tm = fmaxf(fmaxf(s0, s1), fmaxf(s2, s3));
      tm = fmaxf(tm, __shfl_xor(tm, 16, 64));
      tm = fmaxf(tm, __shfl_xor(tm, 32, 64));
      float mnew = fmaxf(sm[nt], tm);
      float corr = __expf(sm[nt] - mnew);
      float e0 = __expf(s0 - mnew), e1 = __expf(s1 - mnew);
      float e2 = __expf(s2 - mnew), e3 = __expf(s3 - mnew);
      float ps = (e0 + e1) + (e2 + e3);
      float pa = e0 * vreg[nt][0] + e1 * vreg[nt][1] + e2 * vreg[nt][2] + e3 * vreg[nt][3];
      ps += __shfl_xor(ps, 16, 64); ps += __shfl_xor(ps, 32, 64);
      pa += __shfl_xor(pa, 16, 64); pa += __shfl_xor(pa, 32, 64);
      sl[nt] = sl[nt] * corr + ps;
      sa[nt] = sa[nt] * corr + pa;
      sm[nt] = mnew;
    }
  }
  __syncthreads();
  if (l < 16){
    #pragma unroll
    for (int nt = 0; nt < 16; ++nt){
      int idx = ((w * 16 + nt) * 16 + l) * 3;
      redbuf[idx] = sm[nt]; redbuf[idx + 1] = sl[nt]; redbuf[idx + 2] = sa[nt];
    }
  }
  __syncthreads();
  if (tid < 256){
    int nt = tid >> 4, f0 = tid & 15;
    float M = -1e30f;
    #pragma unroll
    for (int ww = 0; ww < 8; ++ww) M = fmaxf(M, redbuf[((ww * 16 + nt) * 16 + f0) * 3]);
    float L = 0.f, Ac = 0.f;
    #pragma unroll
    for (int ww = 0; ww < 8; ++ww){
      int idx = ((ww * 16 + nt) * 16 + f0) * 3;
      float e = __expf(redbuf[idx] - M);
      L  += redbuf[idx + 1] * e;
      Ac += redbuf[idx + 2] * e;
    }
    outT[(size_t)bid * 256 + nt * 16 + f0] = f2bf(Ac / L);
  }
}

// ---------------------------------------------------------------- launch
extern "C" void kernel_launch(void* const* d_in, const int* in_sizes, int n_in,
                              void* d_out, int out_size, void* d_ws, size_t ws_size,
                              hipStream_t stream)
{
  const float* tgt  = (const float*)d_in[0];
  const float* mem  = (const float*)d_in[1];
  const float* qpos = (const float*)d_in[2];
  const float* rel  = (const float*)d_in[3];
  const float* ln1g = (const float*)d_in[4];
  const float* ln1b = (const float*)d_in[5];
  const float* ln2g = (const float*)d_in[6];
  const float* ln2b = (const float*)d_in[7];
  const float* ln3g = (const float*)d_in[8];
  const float* ln3b = (const float*)d_in[9];
  const float* inw  = (const float*)d_in[10];
  const float* inb  = (const float*)d_in[11];
  const float* aow  = (const float*)d_in[12];
  const float* aob  = (const float*)d_in[13];
  const float* m1w  = (const float*)d_in[14];
  const float* m1b  = (const float*)d_in[15];
  const float* m2w  = (const float*)d_in[16];
  const float* m2b  = (const float*)d_in[17];
  const float* vw   = (const float*)d_in[18];
  const float* vb   = (const float*)d_in[19];
  const float* ow   = (const float*)d_in[20];
  const float* ob   = (const float*)d_in[21];
  const float* f1w  = (const float*)d_in[22];
  const float* f1b  = (const float*)d_in[23];
  const float* f2w  = (const float*)d_in[24];
  const float* f2b  = (const float*)d_in[25];

  char* ws = (char*)d_ws;
  size_t off = 0;
  auto alloc = [&](size_t bytes) -> char* {
    char* p = ws + off; off += (bytes + 255) & ~size_t(255); return p;
  };
  unsigned short* inw_bf  = (unsigned short*)alloc(768 * 256 * 2);
  unsigned short* aow_bf  = (unsigned short*)alloc(256 * 256 * 2);
  unsigned short* m1w_bf  = (unsigned short*)alloc(256 * 256 * 2);
  unsigned short* m2w_bf  = (unsigned short*)alloc(256 * 256 * 2);
  unsigned short* vw_bf   = (unsigned short*)alloc(256 * 256 * 2);
  unsigned short* ow_bf   = (unsigned short*)alloc(256 * 256 * 2);
  unsigned short* f1w_bf  = (unsigned short*)alloc(1024 * 256 * 2);
  unsigned short* f2w_bf  = (unsigned short*)alloc(256 * 1024 * 2);
  unsigned short* mem_bf  = (unsigned short*)alloc(2048 * 256 * 2);
  unsigned short* t21_bf  = (unsigned short*)alloc(512 * 256 * 2);
  unsigned short* qk_bf   = (unsigned short*)alloc(512 * 256 * 2);
  float*          qkp     = (float*)alloc(512 * 512 * 4);
  float*          vp      = (float*)alloc(512 * 256 * 4);
  unsigned short* ao_bf   = (unsigned short*)alloc(512 * 256 * 2);
  float*          tgta    = (float*)alloc(512 * 256 * 4);
  float*          t22_f   = (float*)alloc(512 * 256 * 4);
  unsigned short* t22_bf  = (unsigned short*)alloc(512 * 256 * 2);
  float*          A1      = (float*)alloc(512 * 256 * 4);
  float*          M1      = (float*)alloc(2048 * 256 * 4);
  float*          Mv      = (float*)alloc(2048 * 256 * 4);
  unsigned short* trel_bf = (unsigned short*)alloc(512 * 256 * 2);
  float*          tgtr    = (float*)alloc(512 * 256 * 4);
  unsigned short* t23_bf  = (unsigned short*)alloc(512 * 256 * 2);
  unsigned short* ffh_bf  = (unsigned short*)alloc(512 * 1024 * 2);

  convert_kernel<<<1536, 256, 0, stream>>>(inw, inw_bf, aow, aow_bf, m1w, m1w_bf,
      m2w, m2w_bf, vw, vw_bf, ow, ow_bf, f1w, f1w_bf, f2w, f2w_bf, mem, mem_bf);

  // ln1 -> tgt2_1 (bf16), qk = tgt2_1 + query_pos (bf16)
  ln_kernel<<<512, 256, 0, stream>>>(tgt, ln1g, ln1b, qpos, nullptr, t21_bf, qk_bf);

  // q|k projection (N=512) and v projection (N=256)
  gemm_kernel<<<dim3(8, 8), 256, 0, stream>>>(qk_bf, inw_bf, inb, nullptr,
      qkp, nullptr, 512, 512, 256, 1.f, 0);
  gemm_kernel<<<dim3(8, 4), 256, 0, stream>>>(t21_bf, inw_bf + 512 * 256, inb + 512, nullptr,
      vp, nullptr, 512, 256, 256, 1.f, 0);

  attn_kernel<<<32, 256, 0, stream>>>(qkp, vp, ao_bf);

  // out-proj + residual tgt -> tgta
  gemm_kernel<<<dim3(8, 4), 256, 0, stream>>>(ao_bf, aow_bf, aob, tgt,
      tgta, nullptr, 512, 256, 256, 1.f, 0);

  // ln2 -> t22 (f32 + bf16)
  ln_kernel<<<512, 256, 0, stream>>>(tgta, ln2g, ln2b, nullptr, t22_f, t22_bf, nullptr);

  // A1 = tgt2@W1 + b1 ; M1 = -mem@W1 ; Mv = mem@Wv + vb
  gemm_kernel<<<dim3(8, 4), 256, 0, stream>>>(t22_bf, m1w_bf, m1b, nullptr,
      A1, nullptr, 512, 256, 256, 1.f, 0);
  gemm_kernel<<<dim3(32, 4), 256, 0, stream>>>(mem_bf, m1w_bf, nullptr, nullptr,
      M1, nullptr, 2048, 256, 256, -1.f, 0);
  gemm_kernel<<<dim3(32, 4), 256, 0, stream>>>(mem_bf, vw_bf, vb, nullptr,
      Mv, nullptr, 2048, 256, 256, 1.f, 0);

  relation_kernel<<<512, 512, 0, stream>>>(rel, A1, M1, Mv, m1w_bf, vw_bf, m2w_bf, m2b, trel_bf);

  // t = relu(t@o_w + o_b) + t22
  gemm_kernel<<<dim3(8, 4), 256, 0, stream>>>(trel_bf, ow_bf, ob, t22_f,
      tgtr, nullptr, 512, 256, 256, 1.f, 1);

  // ln3 -> bf16
  ln_kernel<<<512, 256, 0, stream>>>(tgtr, ln3g, ln3b, nullptr, nullptr, t23_bf, nullptr);

  // ffn
  gemm_kernel<<<dim3(8, 16), 256, 0, stream>>>(t23_bf, f1w_bf, f1b, nullptr,
      nullptr, ffh_bf, 512, 1024, 256, 1.f, 1);
  gemm_kernel<<<dim3(8, 4), 256, 0, stream>>>(ffh_bf, f2w_bf, f2b, tgtr,
      (float*)d_out, nullptr, 512, 256, 1024, 1.f, 0);
}

// Round 2
// 786.623 us; speedup vs baseline: 2.6682x; 2.6682x over previous
//
#include <hip/hip_runtime.h>
#include <hip/hip_bf16.h>
#include <cstdint>
#include <cstddef>

#define DEV __device__ __forceinline__

typedef __attribute__((ext_vector_type(8))) short short8;
typedef __attribute__((ext_vector_type(4))) float f32x4;
typedef __attribute__((ext_vector_type(16))) float f32x16;

constexpr int Dm  = 256;
constexpr int Qn  = 128;
constexpr int Cn  = 512;
constexpr int Bn  = 4;

DEV unsigned short f2bf(float f){
  unsigned int u = __builtin_bit_cast(unsigned int, f);
  u += 0x7fffu + ((u >> 16) & 1u);
  return (unsigned short)(u >> 16);
}

DEV float bfhi2f(unsigned int hi){ return __builtin_bit_cast(float, hi & 0xffff0000u); }
DEV float bflo2f(unsigned int lo){ return __builtin_bit_cast(float, lo << 16); }

DEV f32x4 mfma16(short8 a, short8 b, f32x4 c){
  return __builtin_amdgcn_mfma_f32_16x16x32_bf16(a, b, c, 0, 0, 0);
}
DEV f32x16 mfma32(short8 a, short8 b, f32x16 c){
  return __builtin_amdgcn_mfma_f32_32x32x16_bf16(a, b, c, 0, 0, 0);
}

// 16x16x32 fragment load from XOR-swizzled LDS tile (rowbytes bytes/row)
DEV short8 ldfrag(const unsigned short* buf, int rowbytes, int row0, int ks, int l){
  int r = row0 + (l & 15);
  int byte = (ks * 64 + ((l >> 4) * 16)) ^ ((r & 7) << 4);
  return *(const short8*)((const char*)buf + r * rowbytes + byte);
}

// 32x32x16 A-fragment load from XOR-swizzled LDS tile (512B rows)
DEV short8 ldfrag32(const unsigned short* buf, int row0, int kc, int l){
  int r = row0 + (l & 31);
  int byte = (kc * 32 + ((l >> 5) * 16)) ^ ((r & 7) << 4);
  return *(const short8*)((const char*)buf + r * 512 + byte);
}

// ---------------------------------------------------------------- converts
__global__ __launch_bounds__(256) void conv_lin_kernel(
    const float* s0, unsigned short* d0,   // in_proj 196608
    const float* s1, unsigned short* d1,   // attn_out 65536
    const float* s2, unsigned short* d2,   // o_w 65536
    const float* s3, unsigned short* d3,   // ff1 262144
    const float* s4, unsigned short* d4,   // ff2 262144
    const float* s5, unsigned short* d5,   // memory 524288
    const float* s6, unsigned short* d6)   // v_w 65536
{
  const int total = 196608 + 65536 + 65536 + 262144 + 262144 + 524288 + 65536;
  for (int i = blockIdx.x * 256 + threadIdx.x; i < total; i += gridDim.x * 256){
    int j = i;
    if (j < 196608){ d0[j] = f2bf(s0[j]); continue; } j -= 196608;
    if (j < 65536) { d1[j] = f2bf(s1[j]); continue; } j -= 65536;
    if (j < 65536) { d2[j] = f2bf(s2[j]); continue; } j -= 65536;
    if (j < 262144){ d3[j] = f2bf(s3[j]); continue; } j -= 262144;
    if (j < 262144){ d4[j] = f2bf(s4[j]); continue; } j -= 262144;
    if (j < 524288){ d5[j] = f2bf(s5[j]); continue; } j -= 524288;
    d6[j] = f2bf(s6[j]);
  }
}

// pack weight W[f][d] (256x256) into fragment order:
// out[(d>>3)*2048 + f*8 + (d&7)]  => a 32x32x16 B-frag load is 2x512B contiguous
__global__ __launch_bounds__(256) void conv_pk_kernel(
    const float* s0, unsigned short* d0,
    const float* s1, unsigned short* d1,
    const float* s2, unsigned short* d2)
{
  for (int i = blockIdx.x * 256 + threadIdx.x; i < 3 * 65536; i += gridDim.x * 256){
    int j = i & 65535; int w = i >> 16;
    int f = j >> 8, d = j & 255;
    int dj = (d >> 3) * 2048 + f * 8 + (d & 7);
    const float* s = (w == 0) ? s0 : (w == 1) ? s1 : s2;
    unsigned short* dd = (w == 0) ? d0 : (w == 1) ? d1 : d2;
    dd[dj] = f2bf(s[j]);
  }
}

// ---------------------------------------------------------------- layernorm
__global__ __launch_bounds__(256) void ln_kernel(
    const float* __restrict__ in, const float* __restrict__ g, const float* __restrict__ bt,
    const float* __restrict__ addp,
    float* __restrict__ outF, unsigned short* __restrict__ outA, unsigned short* __restrict__ outB)
{
  const int r = blockIdx.x, t = threadIdx.x;
  float x = in[(size_t)r * 256 + t];
  float s = x, s2 = x * x;
  #pragma unroll
  for (int m = 1; m < 64; m <<= 1){ s += __shfl_xor(s, m, 64); s2 += __shfl_xor(s2, m, 64); }
  __shared__ float ls[8];
  int w = t >> 6, l = t & 63;
  if (l == 0){ ls[w] = s; ls[4 + w] = s2; }
  __syncthreads();
  s  = ls[0] + ls[1] + ls[2] + ls[3];
  s2 = ls[4] + ls[5] + ls[6] + ls[7];
  float mean = s * (1.f / 256.f);
  float var  = s2 * (1.f / 256.f) - mean * mean;
  float y = (x - mean) * rsqrtf(var + 1e-5f) * g[t] + bt[t];
  size_t o = (size_t)r * 256 + t;
  if (outF) outF[o] = y;
  if (outA) outA[o] = f2bf(y);
  if (outB) outB[o] = f2bf(y + addp[o]);
}

// ---------------------------------------------------------------- generic GEMM
// C[M,N] = act(alpha * A_bf16(M,K) @ W_bf16(N,K)^T + bias) (+resid)
// cmode==1: store Cf[((row&3)*256 + col)*512 + (row>>2)]   ([b][f][c] for Mv0T)
__global__ __launch_bounds__(256, 4) void gemm_kernel(
    const unsigned short* __restrict__ A, const unsigned short* __restrict__ W,
    const float* __restrict__ bias, const float* __restrict__ resid,
    float* __restrict__ Cf, unsigned short* __restrict__ Cb,
    int M, int N, int K, float alpha, int relu, int cmode)
{
  __shared__ unsigned short As[64 * 64];
  __shared__ unsigned short Ws[64 * 64];
  const int tid = threadIdx.x;
  const int l = tid & 63;
  const int w = tid >> 6;
  const int wm = w >> 1, wn = w & 1;
  const int bm = blockIdx.x * 64, bn = blockIdx.y * 64;
  f32x4 acc[2][2] = {{{0,0,0,0},{0,0,0,0}},{{0,0,0,0},{0,0,0,0}}};

  for (int kc = 0; kc < K; kc += 64){
    __syncthreads();
    #pragma unroll
    for (int i = 0; i < 2; ++i){
      int idx = tid + i * 256;
      int r = idx >> 3, s = idx & 7;
      int byte = (s * 16) ^ ((r & 7) << 4);
      *(short8*)((char*)As + r * 128 + byte) = *(const short8*)(A + (size_t)(bm + r) * K + kc + s * 8);
      *(short8*)((char*)Ws + r * 128 + byte) = *(const short8*)(W + (size_t)(bn + r) * K + kc + s * 8);
    }
    __syncthreads();
    #pragma unroll
    for (int ks = 0; ks < 2; ++ks){
      short8 af[2], bf[2];
      af[0] = ldfrag(As, 128, wm * 32,      ks, l);
      af[1] = ldfrag(As, 128, wm * 32 + 16, ks, l);
      bf[0] = ldfrag(Ws, 128, wn * 32,      ks, l);
      bf[1] = ldfrag(Ws, 128, wn * 32 + 16, ks, l);
      #pragma unroll
      for (int i = 0; i < 2; ++i)
        #pragma unroll
        for (int j = 0; j < 2; ++j)
          acc[i][j] = mfma16(af[i], bf[j], acc[i][j]);
    }
  }
  #pragma unroll
  for (int i = 0; i < 2; ++i)
  #pragma unroll
  for (int j = 0; j < 2; ++j){
    int col = bn + wn * 32 + j * 16 + (l & 15);
    float bv = bias ? bias[col] : 0.f;
    #pragma unroll
    for (int u = 0; u < 4; ++u){
      int row = bm + wm * 32 + i * 16 + ((l >> 4) << 2) + u;
      float v = alpha * acc[i][j][u] + bv;
      if (relu) v = fmaxf(v, 0.f);
      if (resid) v += resid[(size_t)row * N + col];
      if (cmode == 1){
        Cf[((size_t)(row & 3) * 256 + col) * 512 + (row >> 2)] = v;
      } else {
        if (Cf) Cf[(size_t)row * N + col] = v;
        if (Cb) Cb[(size_t)row * N + col] = f2bf(v);
      }
    }
  }
}

// ---------------------------------------------------------------- self-attention
__global__ __launch_bounds__(256) void attn_kernel(
    const float* __restrict__ qkp, const float* __restrict__ vp,
    unsigned short* __restrict__ attn_o)
{
  __shared__ float ks[128][33];
  __shared__ float vs[128][33];
  __shared__ float sc[128][129];
  const int bh = blockIdx.x;
  const int b = bh >> 3, h = bh & 7;
  const int tid = threadIdx.x;
  const int lrow = tid >> 1;
  const int half = tid & 1;
  {
    int s = tid >> 1;
    int d0 = half * 16;
    const float* kp = qkp + ((size_t)s * Bn + b) * 512 + 256 + h * 32 + d0;
    const float* vv = vp  + ((size_t)s * Bn + b) * 256 +       h * 32 + d0;
    #pragma unroll
    for (int d = 0; d < 16; d += 4){
      *(float4*)&ks[s][d0 + d] = *(const float4*)(kp + d);
      *(float4*)&vs[s][d0 + d] = *(const float4*)(vv + d);
    }
  }
  __syncthreads();
  float qv[32];
  const float* qp = qkp + ((size_t)lrow * Bn + b) * 512 + h * 32;
  #pragma unroll
  for (int d = 0; d < 32; ++d) qv[d] = qp[d];
  const float scale = 0.17677669529663687f;
  float mloc = -1e30f;
  for (int s2 = 0; s2 < 64; ++s2){
    int s = half * 64 + s2;
    float dot = 0.f;
    #pragma unroll
    for (int d = 0; d < 32; ++d) dot += qv[d] * ks[s][d];
    dot *= scale;
    sc[lrow][s] = dot;
    mloc = fmaxf(mloc, dot);
  }
  float m = fmaxf(mloc, __shfl_xor(mloc, 1, 64));
  float sum = 0.f;
  for (int s2 = 0; s2 < 64; ++s2){
    int s = half * 64 + s2;
    float e = __expf(sc[lrow][s] - m);
    sum += e;
    sc[lrow][s] = e;
  }
  sum += __shfl_xor(sum, 1, 64);
  float inv = 1.f / sum;
  float o[32];
  #pragma unroll
  for (int d = 0; d < 32; ++d) o[d] = 0.f;
  for (int s2 = 0; s2 < 64; ++s2){
    int s = half * 64 + s2;
    float e = sc[lrow][s];
    #pragma unroll
    for (int d = 0; d < 32; ++d) o[d] += e * vs[s][d];
  }
  #pragma unroll
  for (int d = 0; d < 32; ++d){
    o[d] += __shfl_xor(o[d], 1, 64);
    o[d] *= inv;
  }
  unsigned short* op = attn_o + ((size_t)lrow * Bn + b) * 256 + h * 32 + half * 16;
  #pragma unroll
  for (int d = 0; d < 16; ++d) op[d] = f2bf(o[half * 16 + d]);
}

// ---------------------------------------------------------------- relation branch (fused)
// block = (q,b), 1024 threads = 16 waves: wr=w>>3 (row half), wc=w&7 (f 32-col)
// x = tgt2 - mem + rel staged in LDS; h = relu(x@W1 + b1) -> hT
// v2 = x@Wv + Mv0T[b,f,c] + T2c[qb,f]  (reuses x frags; Mv0T = 2*mem@Wv, T2c = vb - tgt2@Wv)
// sim = (h@W2 + b2)/16 ; online softmax over c per channel f
__global__ __launch_bounds__(1024, 4) void relation_kernel(
    const float* __restrict__ rel,
    const float* __restrict__ memp,
    const float* __restrict__ tgt2,
    const unsigned short* __restrict__ W1p,
    const unsigned short* __restrict__ Wvp,
    const unsigned short* __restrict__ W2p,
    const float* __restrict__ b1,
    const float* __restrict__ T2c,
    const float* __restrict__ Mv0T,
    const float* __restrict__ b2,
    unsigned short* __restrict__ outT)
{
  __shared__ unsigned short xT[128 * 256];   // 64KB
  __shared__ unsigned short hT[128 * 256];   // 64KB

  const int bid = blockIdx.x;                 // q*4 + b
  const int q = bid >> 2, b = bid & 3;
  const int tid = threadIdx.x;
  const int w = tid >> 6;
  const int l = tid & 63;
  const int wr = w >> 3;                      // 0..1 row half (64 rows)
  const int wc = w & 7;                       // 0..7 f col (32 f)
  const int l31 = l & 31;
  const int kh = l >> 5;
  const int f = wc * 32 + l31;

  const float4 t2v = *(const float4*)(tgt2 + (size_t)bid * 256 + l * 4);
  const float b1v = b1[f];
  const float b2v = b2[f];
  const float tcv = T2c[(size_t)bid * 256 + f];

  const unsigned short* w1base = W1p + ((size_t)kh * 256 + f) * 8;
  const unsigned short* wvbase = Wvp + ((size_t)kh * 256 + f) * 8;
  const unsigned short* w2base = W2p + ((size_t)kh * 256 + f) * 8;

  float sm = -1e30f, sl = 0.f, sa = 0.f;

  for (int ct = 0; ct < 4; ++ct){
    const int c0 = ct * 128;
    // ---- stage x rows [w*8, w*8+8)
    const float* relb = rel + (((size_t)q * Cn + c0 + w * 8) * Bn + b) * Dm + l * 4;
    const float* memb = memp + ((size_t)(c0 + w * 8) * Bn + b) * Dm + l * 4;
    #pragma unroll
    for (int r = 0; r < 8; ++r){
      int row = w * 8 + r;
      const float4 rv = *(const float4*)(relb + (size_t)r * Bn * Dm);
      const float4 mv = *(const float4*)(memb + (size_t)r * Bn * Dm);
      float x0 = t2v.x - mv.x + rv.x;
      float x1 = t2v.y - mv.y + rv.y;
      float x2 = t2v.z - mv.z + rv.z;
      float x3 = t2v.w - mv.w + rv.w;
      unsigned long long pk = (unsigned long long)f2bf(x0)
        | ((unsigned long long)f2bf(x1) << 16)
        | ((unsigned long long)f2bf(x2) << 32)
        | ((unsigned long long)f2bf(x3) << 48);
      int byte = (l * 8) ^ ((row & 7) << 4);
      *(unsigned long long*)((char*)xT + row * 512 + byte) = pk;
    }
    __syncthreads();   // S1: x staged

    // ---- fused GEMM1a (h = x@W1) + GEMM1b (v2 = x@Wv)
    f32x16 acc1[2], accv[2];
    #pragma unroll
    for (int m = 0; m < 2; ++m){
      #pragma unroll
      for (int r = 0; r < 16; ++r){ acc1[m][r] = 0.f; accv[m][r] = 0.f; }
    }
    #pragma unroll
    for (int kc = 0; kc < 16; ++kc){
      short8 a0 = ldfrag32(xT, wr * 64,      kc, l);
      short8 a1 = ldfrag32(xT, wr * 64 + 32, kc, l);
      short8 bw1 = *(const short8*)(w1base + kc * 4096);
      short8 bwv = *(const short8*)(wvbase + kc * 4096);
      acc1[0] = mfma32(a0, bw1, acc1[0]);
      acc1[1] = mfma32(a1, bw1, acc1[1]);
      accv[0] = mfma32(a0, bwv, accv[0]);
      accv[1] = mfma32(a1, bwv, accv[1]);
    }
    // h epilogue -> hT (bf16, swizzled)
    #pragma unroll
    for (int m = 0; m < 2; ++m){
      #pragma unroll
      for (int reg = 0; reg < 16; ++reg){
        int rr = (reg & 3) + 8 * (reg >> 2) + 4 * kh;
        int row = wr * 64 + m * 32 + rr;
        float hv = fmaxf(acc1[m][reg] + b1v, 0.f);
        int byte = (f * 2) ^ ((row & 7) << 4);
        *(unsigned short*)((char*)hT + row * 512 + byte) = f2bf(hv);
      }
    }
    // v2 epilogue -> packed bf16 registers
    unsigned int vreg[2][8];
    #pragma unroll
    for (int m = 0; m < 2; ++m){
      #pragma unroll
      for (int rg = 0; rg < 4; ++rg){
        int cbase = c0 + wr * 64 + m * 32 + rg * 8 + 4 * kh;
        const float4 mv4 = *(const float4*)(Mv0T + ((size_t)b * 256 + f) * 512 + cbase);
        float v0 = accv[m][rg * 4 + 0] + mv4.x + tcv;
        float v1 = accv[m][rg * 4 + 1] + mv4.y + tcv;
        float v2 = accv[m][rg * 4 + 2] + mv4.z + tcv;
        float v3 = accv[m][rg * 4 + 3] + mv4.w + tcv;
        vreg[m][rg * 2 + 0] = (unsigned int)f2bf(v0) | ((unsigned int)f2bf(v1) << 16);
        vreg[m][rg * 2 + 1] = (unsigned int)f2bf(v2) | ((unsigned int)f2bf(v3) << 16);
      }
    }
    __syncthreads();   // S2: h complete

    // ---- GEMM2: sim = (h@W2 + b2)/16
    f32x16 acc2[2];
    #pragma unroll
    for (int m = 0; m < 2; ++m){
      #pragma unroll
      for (int r = 0; r < 16; ++r) acc2[m][r] = 0.f;
    }
    #pragma unroll
    for (int kc = 0; kc < 16; ++kc){
      short8 h0 = ldfrag32(hT, wr * 64,      kc, l);
      short8 h1 = ldfrag32(hT, wr * 64 + 32, kc, l);
      short8 bw2 = *(const short8*)(w2base + kc * 4096);
      acc2[0] = mfma32(h0, bw2, acc2[0]);
      acc2[1] = mfma32(h1, bw2, acc2[1]);
    }
    // online softmax update over this 128-row c-tile
    float tmax = -1e30f;
    #pragma unroll
    for (int m = 0; m < 2; ++m){
      #pragma unroll
      for (int reg = 0; reg < 16; ++reg){
        float sv = (acc2[m][reg] + b2v) * 0.0625f;
        acc2[m][reg] = sv;
        tmax = fmaxf(tmax, sv);
      }
    }
    tmax = fmaxf(tmax, __shfl_xor(tmax, 32, 64));
    float mnew = fmaxf(sm, tmax);
    float corr = __expf(sm - mnew);
    float ps = 0.f, pa = 0.f;
    #pragma unroll
    for (int m = 0; m < 2; ++m){
      #pragma unroll
      for (int rg = 0; rg < 8; ++rg){
        float e0 = __expf(acc2[m][rg * 2 + 0] - mnew);
        float e1 = __expf(acc2[m][rg * 2 + 1] - mnew);
        unsigned int vp2 = vreg[m][rg];
        ps += e0 + e1;
        pa += e0 * bflo2f(vp2) + e1 * bfhi2f(vp2);
      }
    }
    ps += __shfl_xor(ps, 32, 64);
    pa += __shfl_xor(pa, 32, 64);
    sl = sl * corr + ps;
    sa = sa * corr + pa;
    sm = mnew;
  }

  // ---- merge the two wr halves per f
  __syncthreads();
  float* mb = (float*)xT;
  if (l < 32){
    int idx = ((wr * 8 + wc) * 32 + l31) * 3;
    mb[idx] = sm; mb[idx + 1] = sl; mb[idx + 2] = sa;
  }
  __syncthreads();
  if (tid < 256){
    int ff = tid;
    int i0 = ((ff >> 5) * 32 + (ff & 31)) * 3;
    int i1 = ((8 + (ff >> 5)) * 32 + (ff & 31)) * 3;
    float m0 = mb[i0], l0 = mb[i0 + 1], a0 = mb[i0 + 2];
    float m1 = mb[i1], l1 = mb[i1 + 1], a1 = mb[i1 + 2];
    float M = fmaxf(m0, m1);
    float e0 = __expf(m0 - M), e1 = __expf(m1 - M);
    float L = l0 * e0 + l1 * e1;
    float A = a0 * e0 + a1 * e1;
    outT[(size_t)bid * 256 + ff] = f2bf(A / L);
  }
}

// ---------------------------------------------------------------- launch
extern "C" void kernel_launch(void* const* d_in, const int* in_sizes, int n_in,
                              void* d_out, int out_size, void* d_ws, size_t ws_size,
                              hipStream_t stream)
{
  const float* tgt  = (const float*)d_in[0];
  const float* mem  = (const float*)d_in[1];
  const float* qpos = (const float*)d_in[2];
  const float* rel  = (const float*)d_in[3];
  const float* ln1g = (const float*)d_in[4];
  const float* ln1b = (const float*)d_in[5];
  const float* ln2g = (const float*)d_in[6];
  const float* ln2b = (const float*)d_in[7];
  const float* ln3g = (const float*)d_in[8];
  const float* ln3b = (const float*)d_in[9];
  const float* inw  = (const float*)d_in[10];
  const float* inb  = (const float*)d_in[11];
  const float* aow  = (const float*)d_in[12];
  const float* aob  = (const float*)d_in[13];
  const float* m1w  = (const float*)d_in[14];
  const float* m1b  = (const float*)d_in[15];
  const float* m2w  = (const float*)d_in[16];
  const float* m2b  = (const float*)d_in[17];
  const float* vw   = (const float*)d_in[18];
  const float* vb   = (const float*)d_in[19];
  const float* ow   = (const float*)d_in[20];
  const float* ob   = (const float*)d_in[21];
  const float* f1w  = (const float*)d_in[22];
  const float* f1b  = (const float*)d_in[23];
  const float* f2w  = (const float*)d_in[24];
  const float* f2b  = (const float*)d_in[25];

  char* ws = (char*)d_ws;
  size_t off = 0;
  auto alloc = [&](size_t bytes) -> char* {
    char* p = ws + off; off += (bytes + 255) & ~size_t(255); return p;
  };
  unsigned short* inw_bf  = (unsigned short*)alloc(768 * 256 * 2);
  unsigned short* aow_bf  = (unsigned short*)alloc(256 * 256 * 2);
  unsigned short* ow_bf   = (unsigned short*)alloc(256 * 256 * 2);
  unsigned short* f1w_bf  = (unsigned short*)alloc(1024 * 256 * 2);
  unsigned short* f2w_bf  = (unsigned short*)alloc(256 * 1024 * 2);
  unsigned short* mem_bf  = (unsigned short*)alloc(2048 * 256 * 2);
  unsigned short* vw_bf   = (unsigned short*)alloc(256 * 256 * 2);
  unsigned short* m1w_pk  = (unsigned short*)alloc(256 * 256 * 2);
  unsigned short* vw_pk   = (unsigned short*)alloc(256 * 256 * 2);
  unsigned short* m2w_pk  = (unsigned short*)alloc(256 * 256 * 2);
  unsigned short* t21_bf  = (unsigned short*)alloc(512 * 256 * 2);
  unsigned short* qk_bf   = (unsigned short*)alloc(512 * 256 * 2);
  float*          qkp     = (float*)alloc(512 * 512 * 4);
  float*          vp      = (float*)alloc(512 * 256 * 4);
  unsigned short* ao_bf   = (unsigned short*)alloc(512 * 256 * 2);
  float*          tgta    = (float*)alloc(512 * 256 * 4);
  float*          t22_f   = (float*)alloc(512 * 256 * 4);
  unsigned short* t22_bf  = (unsigned short*)alloc(512 * 256 * 2);
  float*          T2c     = (float*)alloc(512 * 256 * 4);
  float*          Mv0T    = (float*)alloc(4 * 256 * 512 * 4);
  unsigned short* trel_bf = (unsigned short*)alloc(512 * 256 * 2);
  float*          tgtr    = (float*)alloc(512 * 256 * 4);
  unsigned short* t23_bf  = (unsigned short*)alloc(512 * 256 * 2);
  unsigned short* ffh_bf  = (unsigned short*)alloc(512 * 1024 * 2);

  conv_lin_kernel<<<2048, 256, 0, stream>>>(inw, inw_bf, aow, aow_bf, ow, ow_bf,
      f1w, f1w_bf, f2w, f2w_bf, mem, mem_bf, vw, vw_bf);
  conv_pk_kernel<<<768, 256, 0, stream>>>(m1w, m1w_pk, vw, vw_pk, m2w, m2w_pk);

  // ln1 -> tgt2_1 (bf16), qk = tgt2_1 + query_pos (bf16)
  ln_kernel<<<512, 256, 0, stream>>>(tgt, ln1g, ln1b, qpos, nullptr, t21_bf, qk_bf);

  // q|k projection (N=512) and v projection (N=256)
  gemm_kernel<<<dim3(8, 8), 256, 0, stream>>>(qk_bf, inw_bf, inb, nullptr,
      qkp, nullptr, 512, 512, 256, 1.f, 0, 0);
  gemm_kernel<<<dim3(8, 4), 256, 0, stream>>>(t21_bf, inw_bf + 512 * 256, inb + 512, nullptr,
      vp, nullptr, 512, 256, 256, 1.f, 0, 0);

  attn_kernel<<<32, 256, 0, stream>>>(qkp, vp, ao_bf);

  // out-proj + residual tgt -> tgta
  gemm_kernel<<<dim3(8, 4), 256, 0, stream>>>(ao_bf, aow_bf, aob, tgt,
      tgta, nullptr, 512, 256, 256, 1.f, 0, 0);

  // ln2 -> t22 (f32 + bf16)
  ln_kernel<<<512, 256, 0, stream>>>(tgta, ln2g, ln2b, nullptr, t22_f, t22_bf, nullptr);

  // T2c = vb - tgt2@Wv ; Mv0T[b][f][c] = 2*mem@Wv
  gemm_kernel<<<dim3(8, 4), 256, 0, stream>>>(t22_bf, vw_bf, vb, nullptr,
      T2c, nullptr, 512, 256, 256, -1.f, 0, 0);
  gemm_kernel<<<dim3(32, 4), 256, 0, stream>>>(mem_bf, vw_bf, nullptr, nullptr,
      Mv0T, nullptr, 2048, 256, 256, 2.f, 0, 1);

  relation_kernel<<<512, 1024, 0, stream>>>(rel, mem, t22_f, m1w_pk, vw_pk, m2w_pk,
      m1b, T2c, Mv0T, m2b, trel_bf);

  // t = relu(t@o_w + o_b) + t22
  gemm_kernel<<<dim3(8, 4), 256, 0, stream>>>(trel_bf, ow_bf, ob, t22_f,
      tgtr, nullptr, 512, 256, 256, 1.f, 1, 0);

  // ln3 -> bf16
  ln_kernel<<<512, 256, 0, stream>>>(tgtr, ln3g, ln3b, nullptr, nullptr, t23_bf, nullptr);

  // ffn
  gemm_kernel<<<dim3(8, 16), 256, 0, stream>>>(t23_bf, f1w_bf, f1b, nullptr,
      nullptr, ffh_bf, 512, 1024, 256, 1.f, 1, 0);
  gemm_kernel<<<dim3(8, 4), 256, 0, stream>>>(ffh_bf, f2w_bf, f2b, tgtr,
      (float*)d_out, nullptr, 512, 256, 1024, 1.f, 0, 0);
}